// Round 4
// baseline (165.510 us; speedup 1.0000x reference)
//
#include <hip/hip_runtime.h>

#define V_CNT 6890
#define N_B 512
#define NP 207          // (24-1)*9
#define RTOT 20670      // V*3
#define JS1_BLKS 192    // 8 chunks x 24 joints
#define FUSE_X 108
#define FUSE_BLKS 864   // 108 x 8, flat with XCD swizzle

typedef unsigned short ushort_t;
typedef __attribute__((ext_vector_type(4))) float f32x4;
typedef __attribute__((ext_vector_type(8))) short s16x8;
typedef __attribute__((ext_vector_type(4))) short s16x4;

// ws layout (bytes)
#define O_PART 0u         // 192*33 f32
#define O_G2   65536u     // 512*512 bf16 = 524288  (G' in B-fragment order)
#define O_A    655360u    // A_swz: 32 ntiles *7*64*8 bf16 = 229376

__device__ __constant__ int PAR[24] = {0,0,0,0,1,2,3,4,5,6,7,8,9,9,9,12,13,14,16,17,18,19,20,21};
__device__ __constant__ int LVL[36] = {
    1, 2, 3,-1,   4, 5, 6,-1,   7, 8, 9,-1,
   10,11,12,13,  14,-1,-1,-1,  15,16,17,-1,
   18,19,-1,-1,  20,21,-1,-1,  22,23,-1,-1};

__device__ __forceinline__ ushort_t f2bf(float f) {
    union { float f; unsigned u; } x; x.f = f;
    unsigned u = x.u + 0x7fffu + ((x.u >> 16) & 1u);
    return (ushort_t)(u >> 16);
}
__device__ __forceinline__ float bf2f(ushort_t h) {
    union { unsigned u; float f; } x; x.u = ((unsigned)h) << 16;
    return x.f;
}
// unaligned (4B) 16-byte load
__device__ __forceinline__ f32x4 ld4u(const float* p) {
    f32x4 v; __builtin_memcpy(&v, p, 16); return v;
}

// ---------- K1: JS/JT partial reduction only ----------
__global__ __launch_bounds__(256) void k_pre(const float* __restrict__ jreg,
                                             const float* __restrict__ sdirs,
                                             const float* __restrict__ vtemp,
                                             float* __restrict__ part) {
    int b2 = blockIdx.x;                 // j*8 + ch
    int tid = threadIdx.x;
    int ch = b2 & 7;
    int j = b2 >> 3;
    int v0 = ch * 862;
    int vend = v0 + 862; if (vend > V_CNT) vend = V_CNT;
    float acc[33];
#pragma unroll
    for (int i = 0; i < 33; i++) acc[i] = 0.f;
    for (int v = v0 + tid; v < vend; v += 256) {
        float r = jreg[j * V_CNT + v];
        const float* sd = sdirs + v * 30;
#pragma unroll
        for (int i = 0; i < 30; i++) acc[i] += r * sd[i];
        acc[30] += r * vtemp[v * 3 + 0];
        acc[31] += r * vtemp[v * 3 + 1];
        acc[32] += r * vtemp[v * 3 + 2];
    }
#pragma unroll
    for (int off = 32; off > 0; off >>= 1) {
#pragma unroll
        for (int i = 0; i < 33; i++) acc[i] += __shfl_down(acc[i], off);
    }
    __shared__ float red[4][33];
    int w = tid >> 6, lane = tid & 63;
    if (lane == 0) {
#pragma unroll
        for (int i = 0; i < 33; i++) red[w][i] = acc[i];
    }
    __syncthreads();
    if (tid < 33) {
        float s = red[0][tid] + red[1][tid] + red[2][tid] + red[3][tid];
        part[b2 * 33 + tid] = s;
    }
}

// ---------- K2: js2 + chain (2 n/block) -> G2 bf16, A_swz bf16 ----------
__global__ __launch_bounds__(128) void k_chain(const float* __restrict__ beta,
                                               const float* __restrict__ pose,
                                               const float* __restrict__ part,
                                               ushort_t* __restrict__ G2,
                                               ushort_t* __restrict__ Aswz) {
    __shared__ float JSl[720];
    __shared__ float JTl[72];
    __shared__ float Rl[2][24][9];
    __shared__ float Jl[2][24][3];
    __shared__ float Tm[2][24][16];
    __shared__ float G[2][24][16];
    __shared__ float Gp[2][24][12];
    int tid = threadIdx.x;

    for (int t = tid; t < 792; t += 128) {
        int j = t / 33, i = t - j * 33;
        float s = 0.f;
#pragma unroll
        for (int c = 0; c < 8; c++) s += part[(j * 8 + c) * 33 + i];
        if (i < 30) JSl[j * 30 + i] = s;
        else        JTl[j * 3 + (i - 30)] = s;
    }
    __syncthreads();

    int sub = tid >> 6, lane = tid & 63;
    int n = blockIdx.x * 2 + sub;

    if (lane < 24) {
        int t = lane;
        float x = pose[n * 72 + t * 3 + 0];
        float y = pose[n * 72 + t * 3 + 1];
        float z = pose[n * 72 + t * 3 + 2];
        float th = sqrtf(x * x + y * y + z * z) + 1e-8f;
        float inv = 1.f / th;
        float rx = x * inv, ry = y * inv, rz = z * inv;
        float c = cosf(th), s = sinf(th), omc = 1.f - c;
        Rl[sub][t][0] = c + omc * rx * rx;
        Rl[sub][t][1] = omc * rx * ry - s * rz;
        Rl[sub][t][2] = omc * rx * rz + s * ry;
        Rl[sub][t][3] = omc * ry * rx + s * rz;
        Rl[sub][t][4] = c + omc * ry * ry;
        Rl[sub][t][5] = omc * ry * rz - s * rx;
        Rl[sub][t][6] = omc * rz * rx - s * ry;
        Rl[sub][t][7] = omc * rz * ry + s * rx;
        Rl[sub][t][8] = c + omc * rz * rz;
#pragma unroll
        for (int cc = 0; cc < 3; cc++) {
            float a = JTl[t * 3 + cc];
#pragma unroll
            for (int b = 0; b < 10; b++) a += beta[n * 10 + b] * JSl[(t * 3 + cc) * 10 + b];
            Jl[sub][t][cc] = a;
        }
    }
    __syncthreads();
    if (lane < 24) {
        int t = lane;
        int p = PAR[t];
        float tx, ty, tz;
        if (t == 0) { tx = Jl[sub][0][0]; ty = Jl[sub][0][1]; tz = Jl[sub][0][2]; }
        else { tx = Jl[sub][t][0] - Jl[sub][p][0]; ty = Jl[sub][t][1] - Jl[sub][p][1]; tz = Jl[sub][t][2] - Jl[sub][p][2]; }
        Tm[sub][t][0] = Rl[sub][t][0]; Tm[sub][t][1] = Rl[sub][t][1]; Tm[sub][t][2]  = Rl[sub][t][2]; Tm[sub][t][3]  = tx;
        Tm[sub][t][4] = Rl[sub][t][3]; Tm[sub][t][5] = Rl[sub][t][4]; Tm[sub][t][6]  = Rl[sub][t][5]; Tm[sub][t][7]  = ty;
        Tm[sub][t][8] = Rl[sub][t][6]; Tm[sub][t][9] = Rl[sub][t][7]; Tm[sub][t][10] = Rl[sub][t][8]; Tm[sub][t][11] = tz;
        Tm[sub][t][12] = 0.f; Tm[sub][t][13] = 0.f; Tm[sub][t][14] = 0.f; Tm[sub][t][15] = 1.f;
    }
    __syncthreads();
    if (lane < 16) G[sub][0][lane] = Tm[sub][0][lane];
    __syncthreads();
#pragma unroll
    for (int p9 = 0; p9 < 9; p9++) {
        int slot = lane >> 4, el = lane & 15;
        int j = LVL[p9 * 4 + slot];
        if (j >= 0) {
            int par = PAR[j];
            int a = el >> 2, bb = el & 3;
            float s = G[sub][par][a * 4 + 0] * Tm[sub][j][0 * 4 + bb]
                    + G[sub][par][a * 4 + 1] * Tm[sub][j][1 * 4 + bb]
                    + G[sub][par][a * 4 + 2] * Tm[sub][j][2 * 4 + bb]
                    + G[sub][par][a * 4 + 3] * Tm[sub][j][3 * 4 + bb];
            G[sub][j][el] = s;
        }
        __syncthreads();
    }
    if (lane < 24) {
        int t = lane;
        float jx = Jl[sub][t][0], jy = Jl[sub][t][1], jz = Jl[sub][t][2];
#pragma unroll
        for (int a = 0; a < 3; a++) {
            float g0 = G[sub][t][a * 4 + 0], g1 = G[sub][t][a * 4 + 1];
            float g2 = G[sub][t][a * 4 + 2], g3 = G[sub][t][a * 4 + 3];
            Gp[sub][t][a * 4 + 0] = g0;
            Gp[sub][t][a * 4 + 1] = g1;
            Gp[sub][t][a * 4 + 2] = g2;
            Gp[sub][t][a * 4 + 3] = g3 - (g0 * jx + g1 * jy + g2 * jz);
        }
    }
    __syncthreads();
    // G2: B-fragment order for the T-MFMA
    {
        int quad = lane >> 4, lm = lane & 15;
        s16x8 pk;
#pragma unroll
        for (int jj = 0; jj < 8; jj++) {
            int joint = quad * 8 + jj;
            float val = (joint < 24 && lm < 12) ? Gp[sub][joint][lm] : 0.f;
            pk[jj] = (short)f2bf(val);
        }
        *(s16x8*)(G2 + (size_t)n * 512 + lane * 8) = pk;
    }
    // A_swz: A-fragment order; lane<28 -> (kc, quad) chunk of 8 k's
    if (lane < 28) {
        int kc = lane >> 2, quad2 = lane & 3;
        s16x8 pk;
#pragma unroll
        for (int j = 0; j < 8; j++) {
            int k = kc * 32 + quad2 * 8 + j;
            float val;
            if (k < NP) {
                int jo = 1 + k / 9;
                int e = k - (jo - 1) * 9;
                float d = (e == 0 || e == 4 || e == 8) ? 1.f : 0.f;
                val = Rl[sub][jo][e] - d;
            } else if (k < 217) {
                val = beta[n * 10 + (k - NP)];
            } else val = 0.f;
            pk[j] = (short)f2bf(val);
        }
        *(s16x8*)(Aswz + (((size_t)(n >> 4) * 7 + kc) * 64 + (quad2 * 16 + (n & 15))) * 8) = pk;
    }
}

// ---------- K3: fused GEMM + LBS, B/W fragments built inline from f32 ----------
// Flat 864-block grid, XCD-bijective swizzle: XCD k (bid%8) owns a contiguous
// ~13.5-bx slab x all 8 by -> its pdirs slice (~2.2MB) + G2 (0.5MB) fit the
// 4MB per-XCD L2, so the 8 by-passes re-read pdirs from L2.
// B fragment (r = rtile*16+lm, k = kc*32+quad*8+i) = pdirs[r][k] for k<207,
// sdirs[r][k-207] for k<217, else 0 -> for kc<6 this is a contiguous 32B
// chunk of pdirs row r; kc=6 is peeled with the generic gather.
__global__ __launch_bounds__(256) void k_fused(const ushort_t* __restrict__ Aswz,
                                               const float* __restrict__ pdirs,
                                               const float* __restrict__ sdirs,
                                               const float* __restrict__ wts,
                                               const ushort_t* __restrict__ G2,
                                               const float* __restrict__ vtemp,
                                               float* __restrict__ out) {
    __shared__ ushort_t vp[4][96][36];    // v_posed^T per wave: [r-local][n-local]
    int bid = blockIdx.x;
    int tt = (bid & 7) * FUSE_X + (bid >> 3);   // bijective 0..863 (864 = 8*108)
    int bx = tt >> 3, by = tt & 7;
    int tid = threadIdx.x, w = tid >> 6, lane = tid & 63;
    int quad = lane >> 4, lm = lane & 15;
    int rh = w & 1, nh = w >> 1;
    int n_w = by * 64 + nh * 32;
    int vs_w = bx * 64 + rh * 32;          // wave's first vertex
    int rtile0 = bx * 12 + rh * 6;
    int ntile0 = by * 4 + nh * 2;

    // per-tile row base pointers + validity (row r depends only on rt)
    const float* prow[6];
    bool rok[6];
#pragma unroll
    for (int rt = 0; rt < 6; rt++) {
        int r = (rtile0 + rt) * 16 + lm;
        rok[rt] = (r < RTOT);
        int rs = rok[rt] ? r : 0;
        prow[rt] = pdirs + (size_t)rs * NP;
    }

    f32x4 acc[2][6];
#pragma unroll
    for (int a = 0; a < 2; a++)
#pragma unroll
        for (int b = 0; b < 6; b++) acc[a][b] = (f32x4)0.f;

    // K-loop kc=0..5: whole chunk inside pdirs (k <= 191 < 207)
#pragma unroll 1
    for (int kc = 0; kc < 6; kc++) {
        s16x8 af[2], bfr[6];
#pragma unroll
        for (int mt = 0; mt < 2; mt++)
            af[mt] = *(const s16x8*)(Aswz + ((size_t)(ntile0 + mt) * 7 + kc) * 512 + lane * 8);
#pragma unroll
        for (int rt = 0; rt < 6; rt++) {
            s16x8 pk = (s16x8)0;
            if (rok[rt]) {
                const float* pr = prow[rt] + kc * 32 + quad * 8;
                f32x4 x0 = ld4u(pr), x1 = ld4u(pr + 4);
#pragma unroll
                for (int i = 0; i < 4; i++) {
                    pk[i]     = (short)f2bf(x0[i]);
                    pk[i + 4] = (short)f2bf(x1[i]);
                }
            }
            bfr[rt] = pk;
        }
#pragma unroll
        for (int mt = 0; mt < 2; mt++)
#pragma unroll
            for (int rt = 0; rt < 6; rt++)
                acc[mt][rt] = __builtin_amdgcn_mfma_f32_16x16x32_bf16(af[mt], bfr[rt], acc[mt][rt], 0, 0, 0);
    }
    // peeled kc=6: k = 192..223 spans pdirs/sdirs/zero
    {
        s16x8 af[2], bfr[6];
#pragma unroll
        for (int mt = 0; mt < 2; mt++)
            af[mt] = *(const s16x8*)(Aswz + ((size_t)(ntile0 + mt) * 7 + 6) * 512 + lane * 8);
#pragma unroll
        for (int rt = 0; rt < 6; rt++) {
            s16x8 pk = (s16x8)0;
            if (rok[rt]) {
                int r = (rtile0 + rt) * 16 + lm;
                const float* pr = prow[rt];
                const float* sr = sdirs + (size_t)r * 10;
#pragma unroll
                for (int i = 0; i < 8; i++) {
                    int k = 192 + quad * 8 + i;
                    float v = 0.f;
                    if (k < NP) v = pr[k];
                    else if (k < 217) v = sr[k - NP];
                    pk[i] = (short)f2bf(v);
                }
            }
            bfr[rt] = pk;
        }
#pragma unroll
        for (int mt = 0; mt < 2; mt++)
#pragma unroll
            for (int rt = 0; rt < 6; rt++)
                acc[mt][rt] = __builtin_amdgcn_mfma_f32_16x16x32_bf16(af[mt], bfr[rt], acc[mt][rt], 0, 0, 0);
    }

    // stage v_posed = acc + vtemp into wave-private LDS (bf16, transposed [rl][nl])
    float vt[6];
#pragma unroll
    for (int rt = 0; rt < 6; rt++) {
        int col = bx * 192 + rh * 96 + rt * 16 + lm;
        vt[rt] = (col < RTOT) ? vtemp[col] : 0.f;
    }
#pragma unroll
    for (int mt = 0; mt < 2; mt++) {
#pragma unroll
        for (int rt = 0; rt < 6; rt++) {
            int rl = rt * 16 + lm;
            int nl0 = mt * 16 + quad * 4;
            s16x4 pk;
            pk[0] = (short)f2bf(acc[mt][rt][0] + vt[rt]);
            pk[1] = (short)f2bf(acc[mt][rt][1] + vt[rt]);
            pk[2] = (short)f2bf(acc[mt][rt][2] + vt[rt]);
            pk[3] = (short)f2bf(acc[mt][rt][3] + vt[rt]);
            *(s16x4*)&vp[w][rl][nl0] = pk;
        }
    }

    // T-MFMA operand W built inline from wts: lane needs wts[v][quad*8..+7],
    // j>=24 (quad 3) and v>=V_CNT -> 0
    s16x8 wf[2];
#pragma unroll
    for (int mt = 0; mt < 2; mt++) {
        int v = vs_w + mt * 16 + lm;
        s16x8 pk = (s16x8)0;
        if (quad < 3 && v < V_CNT) {
            const float* wr = wts + (size_t)v * 24 + quad * 8;
            f32x4 x0 = ld4u(wr), x1 = ld4u(wr + 4);
#pragma unroll
            for (int i = 0; i < 4; i++) {
                pk[i]     = (short)f2bf(x0[i]);
                pk[i + 4] = (short)f2bf(x1[i]);
            }
        }
        wf[mt] = pk;
    }

    // t-loop: 2 n per iteration, G2 double-buffered; T = G'^T x W^T -> lane
    // holds affine row quad of T for vertex lm -> in-register apply + store
    s16x8 ga = *(const s16x8*)(G2 + (size_t)n_w * 512 + lane * 8);
    s16x8 gb = *(const s16x8*)(G2 + (size_t)(n_w + 1) * 512 + lane * 8);
#pragma unroll 1
    for (int t = 0; t < 16; t++) {
        int na = n_w + 2 * t;
        s16x8 gan, gbn;
        if (t < 15) {
            gan = *(const s16x8*)(G2 + (size_t)(na + 2) * 512 + lane * 8);
            gbn = *(const s16x8*)(G2 + (size_t)(na + 3) * 512 + lane * 8);
        }
        f32x4 ta[2], tb[2];
#pragma unroll
        for (int mt = 0; mt < 2; mt++) {
            ta[mt] = __builtin_amdgcn_mfma_f32_16x16x32_bf16(ga, wf[mt], (f32x4)0.f, 0, 0, 0);
            tb[mt] = __builtin_amdgcn_mfma_f32_16x16x32_bf16(gb, wf[mt], (f32x4)0.f, 0, 0, 0);
        }
        if (quad < 3) {
#pragma unroll
            for (int mt = 0; mt < 2; mt++) {
                int v = vs_w + mt * 16 + lm;
                if (v < V_CNT) {
                    int vloc = mt * 16 + lm;
                    unsigned pw0 = *(const unsigned*)&vp[w][vloc * 3 + 0][2 * t];
                    unsigned pw1 = *(const unsigned*)&vp[w][vloc * 3 + 1][2 * t];
                    unsigned pw2 = *(const unsigned*)&vp[w][vloc * 3 + 2][2 * t];
                    float p0a = bf2f((ushort_t)(pw0 & 0xffffu)), p0b = bf2f((ushort_t)(pw0 >> 16));
                    float p1a = bf2f((ushort_t)(pw1 & 0xffffu)), p1b = bf2f((ushort_t)(pw1 >> 16));
                    float p2a = bf2f((ushort_t)(pw2 & 0xffffu)), p2b = bf2f((ushort_t)(pw2 >> 16));
                    float oa = ta[mt][3] + ta[mt][0] * p0a + ta[mt][1] * p1a + ta[mt][2] * p2a;
                    float ob = tb[mt][3] + tb[mt][0] * p0b + tb[mt][1] * p1b + tb[mt][2] * p2b;
                    out[((size_t)na * V_CNT + v) * 3 + quad] = oa;
                    out[((size_t)(na + 1) * V_CNT + v) * 3 + quad] = ob;
                }
            }
        }
        ga = gan; gb = gbn;
    }
}

extern "C" void kernel_launch(void* const* d_in, const int* in_sizes, int n_in,
                              void* d_out, int out_size, void* d_ws, size_t ws_size,
                              hipStream_t stream) {
    const float* beta  = (const float*)d_in[0];
    const float* pose  = (const float*)d_in[1];
    const float* vtemp = (const float*)d_in[2];
    const float* sdirs = (const float*)d_in[3];
    const float* pdirs = (const float*)d_in[4];
    const float* jreg  = (const float*)d_in[5];
    const float* wts   = (const float*)d_in[6];
    char* ws = (char*)d_ws;
    float*    ws_part = (float*)(ws + O_PART);
    ushort_t* ws_G2   = (ushort_t*)(ws + O_G2);
    ushort_t* ws_A    = (ushort_t*)(ws + O_A);
    float* out = (float*)d_out;

    k_pre<<<dim3(JS1_BLKS), dim3(256), 0, stream>>>(jreg, sdirs, vtemp, ws_part);
    k_chain<<<dim3(N_B / 2), dim3(128), 0, stream>>>(beta, pose, ws_part, ws_G2, ws_A);
    k_fused<<<dim3(FUSE_BLKS), dim3(256), 0, stream>>>(ws_A, pdirs, sdirs, wts, ws_G2, vtemp, out);
}

// Round 5
// 128.898 us; speedup vs baseline: 1.2840x; 1.2840x over previous
//
#include <hip/hip_runtime.h>

#define V_CNT 6890
#define N_B 512
#define NP 207          // (24-1)*9
#define RTOT 20670      // V*3
#define BPACK_BLKS 1296 // one rtile per block
#define JS1_BLKS 192    // 8 chunks x 24 joints
#define W_BLKS 27       // 6912/256
#define FUSE_X 108
#define FUSE_BLKS 864   // 108 x 8, flat with XCD swizzle

typedef unsigned short ushort_t;
typedef __attribute__((ext_vector_type(4))) float f32x4;
typedef __attribute__((ext_vector_type(8))) short s16x8;
typedef __attribute__((ext_vector_type(4))) short s16x4;

// ws layout (bytes)
#define O_PART 0u         // 192*33 f32
#define O_G2   65536u     // 512*512 bf16 = 524288  (G' in B-fragment order)
#define O_A    655360u    // A_swz: 32 ntiles *7*64*8 bf16 = 229376
#define O_W    917504u    // 6912*32 bf16 = 442368
#define O_B    1441792u   // B_swz: 1296*7*64*8 bf16 = 9289728

__device__ __constant__ int PAR[24] = {0,0,0,0,1,2,3,4,5,6,7,8,9,9,9,12,13,14,16,17,18,19,20,21};
__device__ __constant__ int LVL[36] = {
    1, 2, 3,-1,   4, 5, 6,-1,   7, 8, 9,-1,
   10,11,12,13,  14,-1,-1,-1,  15,16,17,-1,
   18,19,-1,-1,  20,21,-1,-1,  22,23,-1,-1};

__device__ __forceinline__ ushort_t f2bf(float f) {
    union { float f; unsigned u; } x; x.f = f;
    unsigned u = x.u + 0x7fffu + ((x.u >> 16) & 1u);
    return (ushort_t)(u >> 16);
}
__device__ __forceinline__ float bf2f(ushort_t h) {
    union { unsigned u; float f; } x; x.u = ((unsigned)h) << 16;
    return x.f;
}

// ---------- K1: B_swz pack (LDS-staged, coalesced) | JS/JT partials | W pack ----------
__global__ __launch_bounds__(256) void k_pre(const float* __restrict__ pdirs,
                                             const float* __restrict__ sdirs,
                                             const float* __restrict__ vtemp,
                                             const float* __restrict__ jreg,
                                             const float* __restrict__ wts,
                                             ushort_t* __restrict__ Bswz,
                                             float* __restrict__ part,
                                             ushort_t* __restrict__ Wp) {
    __shared__ float rows[3312];     // 16 rows x 207 f32, contiguous slab of pdirs
    __shared__ float red[4][33];
    int b = blockIdx.x;
    int tid = threadIdx.x;
    if (b < BPACK_BLKS) {
        // stage the block's 16-row pdirs slab with fully-coalesced reads
        int rtile = b;
        int base = rtile * 16 * NP;              // float index
        const int TOTF = RTOT * NP;              // 4278690
        for (int i = tid; i < 16 * NP; i += 256) {
            int gi = base + i;
            rows[i] = (gi < TOTF) ? pdirs[gi] : 0.f;
        }
        __syncthreads();
        // emit 448 fragment chunks (7 kc x 64 lanes), coalesced 16B writes
        for (int c = tid; c < 448; c += 256) {
            int kc = c >> 6, lane = c & 63;
            int quad = lane >> 4, lm = lane & 15;
            int r = rtile * 16 + lm;
            int k0 = kc * 32 + quad * 8;
            bool rv = (r < RTOT);
            s16x8 pk;
#pragma unroll
            for (int i = 0; i < 8; i++) {
                int k = k0 + i;
                float v = 0.f;
                if (rv) {
                    if (k < NP) v = rows[lm * NP + k];
                    else if (k < 217) v = sdirs[(size_t)r * 10 + (k - NP)];
                }
                pk[i] = (short)f2bf(v);
            }
            *(s16x8*)(Bswz + ((size_t)(rtile * 7 + kc) * 64 + lane) * 8) = pk;
        }
    } else if (b < BPACK_BLKS + JS1_BLKS) {
        int b2 = b - BPACK_BLKS;          // j*8 + ch
        int ch = b2 & 7;
        int j = b2 >> 3;
        int v0 = ch * 862;
        int vend = v0 + 862; if (vend > V_CNT) vend = V_CNT;
        float acc[33];
#pragma unroll
        for (int i = 0; i < 33; i++) acc[i] = 0.f;
        for (int v = v0 + tid; v < vend; v += 256) {
            float r = jreg[j * V_CNT + v];
            const float* sd = sdirs + v * 30;
#pragma unroll
            for (int i = 0; i < 30; i++) acc[i] += r * sd[i];
            acc[30] += r * vtemp[v * 3 + 0];
            acc[31] += r * vtemp[v * 3 + 1];
            acc[32] += r * vtemp[v * 3 + 2];
        }
#pragma unroll
        for (int off = 32; off > 0; off >>= 1) {
#pragma unroll
            for (int i = 0; i < 33; i++) acc[i] += __shfl_down(acc[i], off);
        }
        int w = tid >> 6, lane = tid & 63;
        if (lane == 0) {
#pragma unroll
            for (int i = 0; i < 33; i++) red[w][i] = acc[i];
        }
        __syncthreads();
        if (tid < 33) {
            float s = red[0][tid] + red[1][tid] + red[2][tid] + red[3][tid];
            part[b2 * 33 + tid] = s;
        }
    } else {
        int v = (b - BPACK_BLKS - JS1_BLKS) * 256 + tid;   // 0..6911
        ushort_t o[32];
        if (v < V_CNT) {
            const float* wr = wts + v * 24;
#pragma unroll
            for (int j = 0; j < 24; j++) o[j] = f2bf(wr[j]);
        } else {
#pragma unroll
            for (int j = 0; j < 24; j++) o[j] = 0;
        }
#pragma unroll
        for (int j = 24; j < 32; j++) o[j] = 0;
#pragma unroll
        for (int q = 0; q < 4; q++)
            *(s16x8*)(Wp + (size_t)v * 32 + q * 8) = *(s16x8*)&o[q * 8];
    }
}

// ---------- K2: js2 + chain (2 n/block) -> G2 bf16, A_swz bf16 ----------
__global__ __launch_bounds__(128) void k_chain(const float* __restrict__ beta,
                                               const float* __restrict__ pose,
                                               const float* __restrict__ part,
                                               ushort_t* __restrict__ G2,
                                               ushort_t* __restrict__ Aswz) {
    __shared__ float JSl[720];
    __shared__ float JTl[72];
    __shared__ float Rl[2][24][9];
    __shared__ float Jl[2][24][3];
    __shared__ float Tm[2][24][16];
    __shared__ float G[2][24][16];
    __shared__ float Gp[2][24][12];
    int tid = threadIdx.x;

    for (int t = tid; t < 792; t += 128) {
        int j = t / 33, i = t - j * 33;
        float s = 0.f;
#pragma unroll
        for (int c = 0; c < 8; c++) s += part[(j * 8 + c) * 33 + i];
        if (i < 30) JSl[j * 30 + i] = s;
        else        JTl[j * 3 + (i - 30)] = s;
    }
    __syncthreads();

    int sub = tid >> 6, lane = tid & 63;
    int n = blockIdx.x * 2 + sub;

    if (lane < 24) {
        int t = lane;
        float x = pose[n * 72 + t * 3 + 0];
        float y = pose[n * 72 + t * 3 + 1];
        float z = pose[n * 72 + t * 3 + 2];
        float th = sqrtf(x * x + y * y + z * z) + 1e-8f;
        float inv = 1.f / th;
        float rx = x * inv, ry = y * inv, rz = z * inv;
        float c = cosf(th), s = sinf(th), omc = 1.f - c;
        Rl[sub][t][0] = c + omc * rx * rx;
        Rl[sub][t][1] = omc * rx * ry - s * rz;
        Rl[sub][t][2] = omc * rx * rz + s * ry;
        Rl[sub][t][3] = omc * ry * rx + s * rz;
        Rl[sub][t][4] = c + omc * ry * ry;
        Rl[sub][t][5] = omc * ry * rz - s * rx;
        Rl[sub][t][6] = omc * rz * rx - s * ry;
        Rl[sub][t][7] = omc * rz * ry + s * rx;
        Rl[sub][t][8] = c + omc * rz * rz;
#pragma unroll
        for (int cc = 0; cc < 3; cc++) {
            float a = JTl[t * 3 + cc];
#pragma unroll
            for (int b = 0; b < 10; b++) a += beta[n * 10 + b] * JSl[(t * 3 + cc) * 10 + b];
            Jl[sub][t][cc] = a;
        }
    }
    __syncthreads();
    if (lane < 24) {
        int t = lane;
        int p = PAR[t];
        float tx, ty, tz;
        if (t == 0) { tx = Jl[sub][0][0]; ty = Jl[sub][0][1]; tz = Jl[sub][0][2]; }
        else { tx = Jl[sub][t][0] - Jl[sub][p][0]; ty = Jl[sub][t][1] - Jl[sub][p][1]; tz = Jl[sub][t][2] - Jl[sub][p][2]; }
        Tm[sub][t][0] = Rl[sub][t][0]; Tm[sub][t][1] = Rl[sub][t][1]; Tm[sub][t][2]  = Rl[sub][t][2]; Tm[sub][t][3]  = tx;
        Tm[sub][t][4] = Rl[sub][t][3]; Tm[sub][t][5] = Rl[sub][t][4]; Tm[sub][t][6]  = Rl[sub][t][5]; Tm[sub][t][7]  = ty;
        Tm[sub][t][8] = Rl[sub][t][6]; Tm[sub][t][9] = Rl[sub][t][7]; Tm[sub][t][10] = Rl[sub][t][8]; Tm[sub][t][11] = tz;
        Tm[sub][t][12] = 0.f; Tm[sub][t][13] = 0.f; Tm[sub][t][14] = 0.f; Tm[sub][t][15] = 1.f;
    }
    __syncthreads();
    if (lane < 16) G[sub][0][lane] = Tm[sub][0][lane];
    __syncthreads();
#pragma unroll
    for (int p9 = 0; p9 < 9; p9++) {
        int slot = lane >> 4, el = lane & 15;
        int j = LVL[p9 * 4 + slot];
        if (j >= 0) {
            int par = PAR[j];
            int a = el >> 2, bb = el & 3;
            float s = G[sub][par][a * 4 + 0] * Tm[sub][j][0 * 4 + bb]
                    + G[sub][par][a * 4 + 1] * Tm[sub][j][1 * 4 + bb]
                    + G[sub][par][a * 4 + 2] * Tm[sub][j][2 * 4 + bb]
                    + G[sub][par][a * 4 + 3] * Tm[sub][j][3 * 4 + bb];
            G[sub][j][el] = s;
        }
        __syncthreads();
    }
    if (lane < 24) {
        int t = lane;
        float jx = Jl[sub][t][0], jy = Jl[sub][t][1], jz = Jl[sub][t][2];
#pragma unroll
        for (int a = 0; a < 3; a++) {
            float g0 = G[sub][t][a * 4 + 0], g1 = G[sub][t][a * 4 + 1];
            float g2 = G[sub][t][a * 4 + 2], g3 = G[sub][t][a * 4 + 3];
            Gp[sub][t][a * 4 + 0] = g0;
            Gp[sub][t][a * 4 + 1] = g1;
            Gp[sub][t][a * 4 + 2] = g2;
            Gp[sub][t][a * 4 + 3] = g3 - (g0 * jx + g1 * jy + g2 * jz);
        }
    }
    __syncthreads();
    // G2: B-fragment order for the T-MFMA
    {
        int quad = lane >> 4, lm = lane & 15;
        s16x8 pk;
#pragma unroll
        for (int jj = 0; jj < 8; jj++) {
            int joint = quad * 8 + jj;
            float val = (joint < 24 && lm < 12) ? Gp[sub][joint][lm] : 0.f;
            pk[jj] = (short)f2bf(val);
        }
        *(s16x8*)(G2 + (size_t)n * 512 + lane * 8) = pk;
    }
    // A_swz: A-fragment order; lane<28 -> (kc, quad) chunk of 8 k's
    if (lane < 28) {
        int kc = lane >> 2, quad2 = lane & 3;
        s16x8 pk;
#pragma unroll
        for (int j = 0; j < 8; j++) {
            int k = kc * 32 + quad2 * 8 + j;
            float val;
            if (k < NP) {
                int jo = 1 + k / 9;
                int e = k - (jo - 1) * 9;
                float d = (e == 0 || e == 4 || e == 8) ? 1.f : 0.f;
                val = Rl[sub][jo][e] - d;
            } else if (k < 217) {
                val = beta[n * 10 + (k - NP)];
            } else val = 0.f;
            pk[j] = (short)f2bf(val);
        }
        *(s16x8*)(Aswz + (((size_t)(n >> 4) * 7 + kc) * 64 + (quad2 * 16 + (n & 15))) * 8) = pk;
    }
}

// ---------- K3: fused barrier-free GEMM + LBS ----------
// Flat 864-block grid, XCD-bijective swizzle: XCD k (bid%8) owns a contiguous
// ~13.5-bx slab x all 8 by -> its Bswz slice (~1.2MB) + G2 (0.5MB) fit the
// 4MB per-XCD L2, so the 8 by-passes re-read Bswz from L2 instead of L3.
__global__ __launch_bounds__(256) void k_fused(const ushort_t* __restrict__ Aswz,
                                               const ushort_t* __restrict__ Bswz,
                                               const ushort_t* __restrict__ Wp,
                                               const ushort_t* __restrict__ G2,
                                               const float* __restrict__ vtemp,
                                               float* __restrict__ out) {
    __shared__ ushort_t vp[4][96][36];    // v_posed^T per wave: [r-local][n-local], row padded to 36
    int bid = blockIdx.x;
    int tt = (bid & 7) * FUSE_X + (bid >> 3);   // bijective 0..863 (864 = 8*108)
    int bx = tt >> 3, by = tt & 7;
    int tid = threadIdx.x, w = tid >> 6, lane = tid & 63;
    int quad = lane >> 4, lm = lane & 15;
    int rh = w & 1, nh = w >> 1;
    int n_w = by * 64 + nh * 32;
    int vs_w = bx * 64 + rh * 32;          // wave's first vertex
    int rtile0 = bx * 12 + rh * 6;
    int ntile0 = by * 4 + nh * 2;

    f32x4 acc[2][6];
#pragma unroll
    for (int a = 0; a < 2; a++)
#pragma unroll
        for (int b = 0; b < 6; b++) acc[a][b] = (f32x4)0.f;

    // barrier-free K-loop: fragments direct from global (swizzled), 1-deep prefetch
    s16x8 af[2][2], bf[2][6];
#pragma unroll
    for (int mt = 0; mt < 2; mt++)
        af[0][mt] = *(const s16x8*)(Aswz + ((size_t)(ntile0 + mt) * 7 + 0) * 512 + lane * 8);
#pragma unroll
    for (int rt = 0; rt < 6; rt++)
        bf[0][rt] = *(const s16x8*)(Bswz + ((size_t)(rtile0 + rt) * 7 + 0) * 512 + lane * 8);
#pragma unroll
    for (int kc = 0; kc < 7; kc++) {
        int cur = kc & 1, nxt = cur ^ 1;
        if (kc < 6) {
#pragma unroll
            for (int mt = 0; mt < 2; mt++)
                af[nxt][mt] = *(const s16x8*)(Aswz + ((size_t)(ntile0 + mt) * 7 + kc + 1) * 512 + lane * 8);
#pragma unroll
            for (int rt = 0; rt < 6; rt++)
                bf[nxt][rt] = *(const s16x8*)(Bswz + ((size_t)(rtile0 + rt) * 7 + kc + 1) * 512 + lane * 8);
        }
#pragma unroll
        for (int mt = 0; mt < 2; mt++)
#pragma unroll
            for (int rt = 0; rt < 6; rt++)
                acc[mt][rt] = __builtin_amdgcn_mfma_f32_16x16x32_bf16(af[cur][mt], bf[cur][rt], acc[mt][rt], 0, 0, 0);
    }

    // stage v_posed = acc + vtemp into wave-private LDS (bf16, transposed [rl][nl])
    float vt[6];
#pragma unroll
    for (int rt = 0; rt < 6; rt++) {
        int col = bx * 192 + rh * 96 + rt * 16 + lm;
        vt[rt] = (col < RTOT) ? vtemp[col] : 0.f;
    }
#pragma unroll
    for (int mt = 0; mt < 2; mt++) {
#pragma unroll
        for (int rt = 0; rt < 6; rt++) {
            int rl = rt * 16 + lm;
            int nl0 = mt * 16 + quad * 4;
            s16x4 pk;
            pk[0] = (short)f2bf(acc[mt][rt][0] + vt[rt]);
            pk[1] = (short)f2bf(acc[mt][rt][1] + vt[rt]);
            pk[2] = (short)f2bf(acc[mt][rt][2] + vt[rt]);
            pk[3] = (short)f2bf(acc[mt][rt][3] + vt[rt]);
            *(s16x4*)&vp[w][rl][nl0] = pk;
        }
    }

    // T-MFMA operand W (hoisted; B-fragment: cols = this wave's 32 vertices)
    s16x8 wf[2];
#pragma unroll
    for (int mt = 0; mt < 2; mt++)
        wf[mt] = *(const s16x8*)(Wp + (size_t)(vs_w + mt * 16 + lm) * 32 + quad * 8);

    // t-loop: 2 n per iteration, G2 double-buffered; T = G'^T x W^T -> lane
    // holds affine row quad of T for vertex lm -> in-register apply + store
    s16x8 ga = *(const s16x8*)(G2 + (size_t)n_w * 512 + lane * 8);
    s16x8 gb = *(const s16x8*)(G2 + (size_t)(n_w + 1) * 512 + lane * 8);
#pragma unroll 1
    for (int t = 0; t < 16; t++) {
        int na = n_w + 2 * t;
        s16x8 gan, gbn;
        if (t < 15) {
            gan = *(const s16x8*)(G2 + (size_t)(na + 2) * 512 + lane * 8);
            gbn = *(const s16x8*)(G2 + (size_t)(na + 3) * 512 + lane * 8);
        }
        f32x4 ta[2], tb[2];
#pragma unroll
        for (int mt = 0; mt < 2; mt++) {
            ta[mt] = __builtin_amdgcn_mfma_f32_16x16x32_bf16(ga, wf[mt], (f32x4)0.f, 0, 0, 0);
            tb[mt] = __builtin_amdgcn_mfma_f32_16x16x32_bf16(gb, wf[mt], (f32x4)0.f, 0, 0, 0);
        }
        if (quad < 3) {
#pragma unroll
            for (int mt = 0; mt < 2; mt++) {
                int v = vs_w + mt * 16 + lm;
                if (v < V_CNT) {
                    int vloc = mt * 16 + lm;
                    unsigned pw0 = *(const unsigned*)&vp[w][vloc * 3 + 0][2 * t];
                    unsigned pw1 = *(const unsigned*)&vp[w][vloc * 3 + 1][2 * t];
                    unsigned pw2 = *(const unsigned*)&vp[w][vloc * 3 + 2][2 * t];
                    float p0a = bf2f((ushort_t)(pw0 & 0xffffu)), p0b = bf2f((ushort_t)(pw0 >> 16));
                    float p1a = bf2f((ushort_t)(pw1 & 0xffffu)), p1b = bf2f((ushort_t)(pw1 >> 16));
                    float p2a = bf2f((ushort_t)(pw2 & 0xffffu)), p2b = bf2f((ushort_t)(pw2 >> 16));
                    float oa = ta[mt][3] + ta[mt][0] * p0a + ta[mt][1] * p1a + ta[mt][2] * p2a;
                    float ob = tb[mt][3] + tb[mt][0] * p0b + tb[mt][1] * p1b + tb[mt][2] * p2b;
                    out[((size_t)na * V_CNT + v) * 3 + quad] = oa;
                    out[((size_t)(na + 1) * V_CNT + v) * 3 + quad] = ob;
                }
            }
        }
        ga = gan; gb = gbn;
    }
}

extern "C" void kernel_launch(void* const* d_in, const int* in_sizes, int n_in,
                              void* d_out, int out_size, void* d_ws, size_t ws_size,
                              hipStream_t stream) {
    const float* beta  = (const float*)d_in[0];
    const float* pose  = (const float*)d_in[1];
    const float* vtemp = (const float*)d_in[2];
    const float* sdirs = (const float*)d_in[3];
    const float* pdirs = (const float*)d_in[4];
    const float* jreg  = (const float*)d_in[5];
    const float* wts   = (const float*)d_in[6];
    char* ws = (char*)d_ws;
    float*    ws_part = (float*)(ws + O_PART);
    ushort_t* ws_G2   = (ushort_t*)(ws + O_G2);
    ushort_t* ws_A    = (ushort_t*)(ws + O_A);
    ushort_t* ws_W    = (ushort_t*)(ws + O_W);
    ushort_t* ws_B    = (ushort_t*)(ws + O_B);
    float* out = (float*)d_out;

    k_pre<<<dim3(BPACK_BLKS + JS1_BLKS + W_BLKS), dim3(256), 0, stream>>>(
        pdirs, sdirs, vtemp, jreg, wts, ws_B, ws_part, ws_W);
    k_chain<<<dim3(N_B / 2), dim3(128), 0, stream>>>(beta, pose, ws_part, ws_G2, ws_A);
    k_fused<<<dim3(FUSE_BLKS), dim3(256), 0, stream>>>(ws_A, ws_B, ws_W, ws_G2, vtemp, out);
}

// Round 6
// 125.134 us; speedup vs baseline: 1.3227x; 1.0301x over previous
//
#include <hip/hip_runtime.h>

#define V_CNT 6890
#define N_B 512
#define NP 207          // (24-1)*9
#define RTOT 20670      // V*3
#define CHAIN_BLKS 128  // 4 n per block, 256 thr
#define BPACK_BLKS 1296 // one rtile per block
#define W_BLKS 27       // 6912/256
#define PREP_BLKS (CHAIN_BLKS + BPACK_BLKS + W_BLKS)
#define JS1_BLKS 192    // 8 chunks x 24 joints
#define FUSE_X 108
#define FUSE_BLKS 864   // 108 x 8, flat with XCD swizzle

typedef unsigned short ushort_t;
typedef __attribute__((ext_vector_type(4))) float f32x4;
typedef __attribute__((ext_vector_type(8))) short s16x8;
typedef __attribute__((ext_vector_type(4))) short s16x4;

// ws layout (bytes)
#define O_PART 0u         // 192*33 f32
#define O_G2   65536u     // 512*512 bf16 = 524288  (G' in B-fragment order)
#define O_A    655360u    // A_swz: 32 ntiles *7*64*8 bf16 = 229376
#define O_W    917504u    // 6912*32 bf16 = 442368
#define O_B    1441792u   // B_swz: 1296*7*64*8 bf16 = 9289728

__device__ __constant__ int PAR[24] = {0,0,0,0,1,2,3,4,5,6,7,8,9,9,9,12,13,14,16,17,18,19,20,21};
__device__ __constant__ int LVL[36] = {
    1, 2, 3,-1,   4, 5, 6,-1,   7, 8, 9,-1,
   10,11,12,13,  14,-1,-1,-1,  15,16,17,-1,
   18,19,-1,-1,  20,21,-1,-1,  22,23,-1,-1};

__device__ __forceinline__ ushort_t f2bf(float f) {
    union { float f; unsigned u; } x; x.f = f;
    unsigned u = x.u + 0x7fffu + ((x.u >> 16) & 1u);
    return (ushort_t)(u >> 16);
}
__device__ __forceinline__ float bf2f(ushort_t h) {
    union { unsigned u; float f; } x; x.u = ((unsigned)h) << 16;
    return x.f;
}

// ---------- K0: JS/JT partial reduction ----------
__global__ __launch_bounds__(256) void k_js(const float* __restrict__ jreg,
                                            const float* __restrict__ sdirs,
                                            const float* __restrict__ vtemp,
                                            float* __restrict__ part) {
    __shared__ float red[4][33];
    int b2 = blockIdx.x;                 // j*8 + ch
    int tid = threadIdx.x;
    int ch = b2 & 7;
    int j = b2 >> 3;
    int v0 = ch * 862;
    int vend = v0 + 862; if (vend > V_CNT) vend = V_CNT;
    float acc[33];
#pragma unroll
    for (int i = 0; i < 33; i++) acc[i] = 0.f;
    for (int v = v0 + tid; v < vend; v += 256) {
        float r = jreg[j * V_CNT + v];
        const float* sd = sdirs + v * 30;
#pragma unroll
        for (int i = 0; i < 30; i++) acc[i] += r * sd[i];
        acc[30] += r * vtemp[v * 3 + 0];
        acc[31] += r * vtemp[v * 3 + 1];
        acc[32] += r * vtemp[v * 3 + 2];
    }
#pragma unroll
    for (int off = 32; off > 0; off >>= 1) {
#pragma unroll
        for (int i = 0; i < 33; i++) acc[i] += __shfl_down(acc[i], off);
    }
    int w = tid >> 6, lane = tid & 63;
    if (lane == 0) {
#pragma unroll
        for (int i = 0; i < 33; i++) red[w][i] = acc[i];
    }
    __syncthreads();
    if (tid < 33) {
        float s = red[0][tid] + red[1][tid] + red[2][tid] + red[3][tid];
        part[b2 * 33 + tid] = s;
    }
}

// ---------- K1: chain (4 n/block) first || B_swz pack || W pack ----------
__global__ __launch_bounds__(256) void k_prep(const float* __restrict__ beta,
                                              const float* __restrict__ pose,
                                              const float* __restrict__ part,
                                              const float* __restrict__ pdirs,
                                              const float* __restrict__ sdirs,
                                              const float* __restrict__ wts,
                                              ushort_t* __restrict__ G2,
                                              ushort_t* __restrict__ Aswz,
                                              ushort_t* __restrict__ Bswz,
                                              ushort_t* __restrict__ Wp) {
    __shared__ __align__(16) char smem[24672];
    int b = blockIdx.x;
    int tid = threadIdx.x;

    if (b < CHAIN_BLKS) {
        // ---- kinematic chain, 4 n per block (verified dev_chain4 structure) ----
        float* smem_f = (float*)smem;
        float* JSl = smem_f;                                     // 720
        float* JTl = smem_f + 720;                               // 72
        float (*Rl)[24][9]  = (float (*)[24][9])(smem_f + 792);  // 4*216
        float (*Jl)[24][3]  = (float (*)[24][3])(smem_f + 1656); // 4*72
        float (*Tm)[24][16] = (float (*)[24][16])(smem_f + 1944);// 4*384
        float (*G )[24][16] = (float (*)[24][16])(smem_f + 3480);// 4*384
        float (*Gp)[24][12] = (float (*)[24][12])(smem_f + 5016);// 4*288

        for (int t = tid; t < 792; t += 256) {
            int j = t / 33, i = t - j * 33;
            float s = 0.f;
#pragma unroll
            for (int c = 0; c < 8; c++) s += part[(j * 8 + c) * 33 + i];
            if (i < 30) JSl[j * 30 + i] = s;
            else        JTl[j * 3 + (i - 30)] = s;
        }
        __syncthreads();

        int sub = tid >> 6, lane = tid & 63;
        int n = b * 4 + sub;

        if (lane < 24) {
            int t = lane;
            float x = pose[n * 72 + t * 3 + 0];
            float y = pose[n * 72 + t * 3 + 1];
            float z = pose[n * 72 + t * 3 + 2];
            float th = sqrtf(x * x + y * y + z * z) + 1e-8f;
            float inv = 1.f / th;
            float rx = x * inv, ry = y * inv, rz = z * inv;
            float c = cosf(th), s = sinf(th), omc = 1.f - c;
            Rl[sub][t][0] = c + omc * rx * rx;
            Rl[sub][t][1] = omc * rx * ry - s * rz;
            Rl[sub][t][2] = omc * rx * rz + s * ry;
            Rl[sub][t][3] = omc * ry * rx + s * rz;
            Rl[sub][t][4] = c + omc * ry * ry;
            Rl[sub][t][5] = omc * ry * rz - s * rx;
            Rl[sub][t][6] = omc * rz * rx - s * ry;
            Rl[sub][t][7] = omc * rz * ry + s * rx;
            Rl[sub][t][8] = c + omc * rz * rz;
#pragma unroll
            for (int cc = 0; cc < 3; cc++) {
                float a = JTl[t * 3 + cc];
#pragma unroll
                for (int bb = 0; bb < 10; bb++) a += beta[n * 10 + bb] * JSl[(t * 3 + cc) * 10 + bb];
                Jl[sub][t][cc] = a;
            }
        }
        __syncthreads();
        if (lane < 24) {
            int t = lane;
            int p = PAR[t];
            float tx, ty, tz;
            if (t == 0) { tx = Jl[sub][0][0]; ty = Jl[sub][0][1]; tz = Jl[sub][0][2]; }
            else { tx = Jl[sub][t][0] - Jl[sub][p][0]; ty = Jl[sub][t][1] - Jl[sub][p][1]; tz = Jl[sub][t][2] - Jl[sub][p][2]; }
            Tm[sub][t][0] = Rl[sub][t][0]; Tm[sub][t][1] = Rl[sub][t][1]; Tm[sub][t][2]  = Rl[sub][t][2]; Tm[sub][t][3]  = tx;
            Tm[sub][t][4] = Rl[sub][t][3]; Tm[sub][t][5] = Rl[sub][t][4]; Tm[sub][t][6]  = Rl[sub][t][5]; Tm[sub][t][7]  = ty;
            Tm[sub][t][8] = Rl[sub][t][6]; Tm[sub][t][9] = Rl[sub][t][7]; Tm[sub][t][10] = Rl[sub][t][8]; Tm[sub][t][11] = tz;
            Tm[sub][t][12] = 0.f; Tm[sub][t][13] = 0.f; Tm[sub][t][14] = 0.f; Tm[sub][t][15] = 1.f;
        }
        __syncthreads();
        if (lane < 16) G[sub][0][lane] = Tm[sub][0][lane];
        __syncthreads();
#pragma unroll
        for (int p9 = 0; p9 < 9; p9++) {
            int slot = lane >> 4, el = lane & 15;
            int j = LVL[p9 * 4 + slot];
            if (j >= 0) {
                int par = PAR[j];
                int a = el >> 2, bb = el & 3;
                float s = G[sub][par][a * 4 + 0] * Tm[sub][j][0 * 4 + bb]
                        + G[sub][par][a * 4 + 1] * Tm[sub][j][1 * 4 + bb]
                        + G[sub][par][a * 4 + 2] * Tm[sub][j][2 * 4 + bb]
                        + G[sub][par][a * 4 + 3] * Tm[sub][j][3 * 4 + bb];
                G[sub][j][el] = s;
            }
            __syncthreads();
        }
        if (lane < 24) {
            int t = lane;
            float jx = Jl[sub][t][0], jy = Jl[sub][t][1], jz = Jl[sub][t][2];
#pragma unroll
            for (int a = 0; a < 3; a++) {
                float g0 = G[sub][t][a * 4 + 0], g1 = G[sub][t][a * 4 + 1];
                float g2 = G[sub][t][a * 4 + 2], g3 = G[sub][t][a * 4 + 3];
                Gp[sub][t][a * 4 + 0] = g0;
                Gp[sub][t][a * 4 + 1] = g1;
                Gp[sub][t][a * 4 + 2] = g2;
                Gp[sub][t][a * 4 + 3] = g3 - (g0 * jx + g1 * jy + g2 * jz);
            }
        }
        __syncthreads();
        // G2: B-fragment order for the T-MFMA
        {
            int quad = lane >> 4, lm = lane & 15;
            s16x8 pk;
#pragma unroll
            for (int jj = 0; jj < 8; jj++) {
                int joint = quad * 8 + jj;
                float val = (joint < 24 && lm < 12) ? Gp[sub][joint][lm] : 0.f;
                pk[jj] = (short)f2bf(val);
            }
            *(s16x8*)(G2 + (size_t)n * 512 + lane * 8) = pk;
        }
        // A_swz: A-fragment order; lane<28 -> (kc, quad) chunk of 8 k's
        if (lane < 28) {
            int kc = lane >> 2, quad2 = lane & 3;
            s16x8 pk;
#pragma unroll
            for (int j = 0; j < 8; j++) {
                int k = kc * 32 + quad2 * 8 + j;
                float val;
                if (k < NP) {
                    int jo = 1 + k / 9;
                    int e = k - (jo - 1) * 9;
                    float d = (e == 0 || e == 4 || e == 8) ? 1.f : 0.f;
                    val = Rl[sub][jo][e] - d;
                } else if (k < 217) {
                    val = beta[n * 10 + (k - NP)];
                } else val = 0.f;
                pk[j] = (short)f2bf(val);
            }
            *(s16x8*)(Aswz + (((size_t)(n >> 4) * 7 + kc) * 64 + (quad2 * 16 + (n & 15))) * 8) = pk;
        }
    } else if (b < CHAIN_BLKS + BPACK_BLKS) {
        // ---- B_swz pack: LDS-staged, coalesced (round-5 verified) ----
        float* rows = (float*)smem;              // 16 rows x 207 f32
        int rtile = b - CHAIN_BLKS;
        int base = rtile * 16 * NP;              // float index
        const int TOTF = RTOT * NP;              // 4278690
        for (int i = tid; i < 16 * NP; i += 256) {
            int gi = base + i;
            rows[i] = (gi < TOTF) ? pdirs[gi] : 0.f;
        }
        __syncthreads();
        for (int c = tid; c < 448; c += 256) {
            int kc = c >> 6, lane = c & 63;
            int quad = lane >> 4, lm = lane & 15;
            int r = rtile * 16 + lm;
            int k0 = kc * 32 + quad * 8;
            bool rv = (r < RTOT);
            s16x8 pk;
#pragma unroll
            for (int i = 0; i < 8; i++) {
                int k = k0 + i;
                float v = 0.f;
                if (rv) {
                    if (k < NP) v = rows[lm * NP + k];
                    else if (k < 217) v = sdirs[(size_t)r * 10 + (k - NP)];
                }
                pk[i] = (short)f2bf(v);
            }
            *(s16x8*)(Bswz + ((size_t)(rtile * 7 + kc) * 64 + lane) * 8) = pk;
        }
    } else {
        // ---- W pack ----
        int v = (b - CHAIN_BLKS - BPACK_BLKS) * 256 + tid;   // 0..6911
        ushort_t o[32];
        if (v < V_CNT) {
            const float* wr = wts + v * 24;
#pragma unroll
            for (int j = 0; j < 24; j++) o[j] = f2bf(wr[j]);
        } else {
#pragma unroll
            for (int j = 0; j < 24; j++) o[j] = 0;
        }
#pragma unroll
        for (int j = 24; j < 32; j++) o[j] = 0;
#pragma unroll
        for (int q = 0; q < 4; q++)
            *(s16x8*)(Wp + (size_t)v * 32 + q * 8) = *(s16x8*)&o[q * 8];
    }
}

// ---------- K2: fused barrier-free GEMM + LBS ----------
// Flat 864-block grid with XCD-bijective swizzle. t-loop processes 4 n per
// iteration with next-iteration G2 loads issued before the apply (4-ahead).
__global__ __launch_bounds__(256) void k_fused(const ushort_t* __restrict__ Aswz,
                                               const ushort_t* __restrict__ Bswz,
                                               const ushort_t* __restrict__ Wp,
                                               const ushort_t* __restrict__ G2,
                                               const float* __restrict__ vtemp,
                                               float* __restrict__ out) {
    __shared__ ushort_t vp[4][96][36];    // v_posed^T per wave: [r-local][n-local]
    int bid = blockIdx.x;
    int tt = (bid & 7) * FUSE_X + (bid >> 3);   // bijective 0..863 (864 = 8*108)
    int bx = tt >> 3, by = tt & 7;
    int tid = threadIdx.x, w = tid >> 6, lane = tid & 63;
    int quad = lane >> 4, lm = lane & 15;
    int rh = w & 1, nh = w >> 1;
    int n_w = by * 64 + nh * 32;
    int vs_w = bx * 64 + rh * 32;          // wave's first vertex
    int rtile0 = bx * 12 + rh * 6;
    int ntile0 = by * 4 + nh * 2;

    f32x4 acc[2][6];
#pragma unroll
    for (int a = 0; a < 2; a++)
#pragma unroll
        for (int b = 0; b < 6; b++) acc[a][b] = (f32x4)0.f;

    // barrier-free K-loop: fragments direct from global (swizzled), 1-deep prefetch
    s16x8 af[2][2], bf[2][6];
#pragma unroll
    for (int mt = 0; mt < 2; mt++)
        af[0][mt] = *(const s16x8*)(Aswz + ((size_t)(ntile0 + mt) * 7 + 0) * 512 + lane * 8);
#pragma unroll
    for (int rt = 0; rt < 6; rt++)
        bf[0][rt] = *(const s16x8*)(Bswz + ((size_t)(rtile0 + rt) * 7 + 0) * 512 + lane * 8);
#pragma unroll
    for (int kc = 0; kc < 7; kc++) {
        int cur = kc & 1, nxt = cur ^ 1;
        if (kc < 6) {
#pragma unroll
            for (int mt = 0; mt < 2; mt++)
                af[nxt][mt] = *(const s16x8*)(Aswz + ((size_t)(ntile0 + mt) * 7 + kc + 1) * 512 + lane * 8);
#pragma unroll
            for (int rt = 0; rt < 6; rt++)
                bf[nxt][rt] = *(const s16x8*)(Bswz + ((size_t)(rtile0 + rt) * 7 + kc + 1) * 512 + lane * 8);
        }
#pragma unroll
        for (int mt = 0; mt < 2; mt++)
#pragma unroll
            for (int rt = 0; rt < 6; rt++)
                acc[mt][rt] = __builtin_amdgcn_mfma_f32_16x16x32_bf16(af[cur][mt], bf[cur][rt], acc[mt][rt], 0, 0, 0);
    }

    // stage v_posed = acc + vtemp into wave-private LDS (bf16, transposed [rl][nl])
    float vt[6];
#pragma unroll
    for (int rt = 0; rt < 6; rt++) {
        int col = bx * 192 + rh * 96 + rt * 16 + lm;
        vt[rt] = (col < RTOT) ? vtemp[col] : 0.f;
    }
#pragma unroll
    for (int mt = 0; mt < 2; mt++) {
#pragma unroll
        for (int rt = 0; rt < 6; rt++) {
            int rl = rt * 16 + lm;
            int nl0 = mt * 16 + quad * 4;
            s16x4 pk;
            pk[0] = (short)f2bf(acc[mt][rt][0] + vt[rt]);
            pk[1] = (short)f2bf(acc[mt][rt][1] + vt[rt]);
            pk[2] = (short)f2bf(acc[mt][rt][2] + vt[rt]);
            pk[3] = (short)f2bf(acc[mt][rt][3] + vt[rt]);
            *(s16x4*)&vp[w][rl][nl0] = pk;
        }
    }

    // T-MFMA operand W (hoisted; B-fragment: cols = this wave's 32 vertices)
    s16x8 wf[2];
#pragma unroll
    for (int mt = 0; mt < 2; mt++)
        wf[mt] = *(const s16x8*)(Wp + (size_t)(vs_w + mt * 16 + lm) * 32 + quad * 8);

    // t-loop: 4 n per iteration, next 4 G2 rows prefetched before the apply.
    // T = G'^T x W^T -> lane (quad,lm) holds affine row quad of T for vertex lm.
#define LDG2(nn) (*(const s16x8*)(G2 + (size_t)(nn) * 512 + lane * 8))
    s16x8 gaE = LDG2(n_w + 0), gbE = LDG2(n_w + 1);
    s16x8 gaO = LDG2(n_w + 2), gbO = LDG2(n_w + 3);
#pragma unroll 1
    for (int t2 = 0; t2 < 8; t2++) {
        int na = n_w + 4 * t2;
        s16x8 nE0, nE1, nO0, nO1;
        if (t2 < 7) {
            nE0 = LDG2(na + 4); nE1 = LDG2(na + 5);
            nO0 = LDG2(na + 6); nO1 = LDG2(na + 7);
        }
        f32x4 ta[2], tb[2], tc[2], td[2];
#pragma unroll
        for (int mt = 0; mt < 2; mt++) {
            ta[mt] = __builtin_amdgcn_mfma_f32_16x16x32_bf16(gaE, wf[mt], (f32x4)0.f, 0, 0, 0);
            tb[mt] = __builtin_amdgcn_mfma_f32_16x16x32_bf16(gbE, wf[mt], (f32x4)0.f, 0, 0, 0);
            tc[mt] = __builtin_amdgcn_mfma_f32_16x16x32_bf16(gaO, wf[mt], (f32x4)0.f, 0, 0, 0);
            td[mt] = __builtin_amdgcn_mfma_f32_16x16x32_bf16(gbO, wf[mt], (f32x4)0.f, 0, 0, 0);
        }
        if (quad < 3) {
            int c0 = 4 * t2;
#pragma unroll
            for (int mt = 0; mt < 2; mt++) {
                int v = vs_w + mt * 16 + lm;
                if (v < V_CNT) {
                    int vloc = mt * 16 + lm;
                    // even n-pair (na, na+1)
                    unsigned pw0 = *(const unsigned*)&vp[w][vloc * 3 + 0][c0];
                    unsigned pw1 = *(const unsigned*)&vp[w][vloc * 3 + 1][c0];
                    unsigned pw2 = *(const unsigned*)&vp[w][vloc * 3 + 2][c0];
                    float p0a = bf2f((ushort_t)(pw0 & 0xffffu)), p0b = bf2f((ushort_t)(pw0 >> 16));
                    float p1a = bf2f((ushort_t)(pw1 & 0xffffu)), p1b = bf2f((ushort_t)(pw1 >> 16));
                    float p2a = bf2f((ushort_t)(pw2 & 0xffffu)), p2b = bf2f((ushort_t)(pw2 >> 16));
                    float oa = ta[mt][3] + ta[mt][0] * p0a + ta[mt][1] * p1a + ta[mt][2] * p2a;
                    float ob = tb[mt][3] + tb[mt][0] * p0b + tb[mt][1] * p1b + tb[mt][2] * p2b;
                    out[((size_t)na * V_CNT + v) * 3 + quad] = oa;
                    out[((size_t)(na + 1) * V_CNT + v) * 3 + quad] = ob;
                    // odd n-pair (na+2, na+3)
                    unsigned qw0 = *(const unsigned*)&vp[w][vloc * 3 + 0][c0 + 2];
                    unsigned qw1 = *(const unsigned*)&vp[w][vloc * 3 + 1][c0 + 2];
                    unsigned qw2 = *(const unsigned*)&vp[w][vloc * 3 + 2][c0 + 2];
                    float q0a = bf2f((ushort_t)(qw0 & 0xffffu)), q0b = bf2f((ushort_t)(qw0 >> 16));
                    float q1a = bf2f((ushort_t)(qw1 & 0xffffu)), q1b = bf2f((ushort_t)(qw1 >> 16));
                    float q2a = bf2f((ushort_t)(qw2 & 0xffffu)), q2b = bf2f((ushort_t)(qw2 >> 16));
                    float oc = tc[mt][3] + tc[mt][0] * q0a + tc[mt][1] * q1a + tc[mt][2] * q2a;
                    float od = td[mt][3] + td[mt][0] * q0b + td[mt][1] * q1b + td[mt][2] * q2b;
                    out[((size_t)(na + 2) * V_CNT + v) * 3 + quad] = oc;
                    out[((size_t)(na + 3) * V_CNT + v) * 3 + quad] = od;
                }
            }
        }
        gaE = nE0; gbE = nE1; gaO = nO0; gbO = nO1;
    }
#undef LDG2
}

extern "C" void kernel_launch(void* const* d_in, const int* in_sizes, int n_in,
                              void* d_out, int out_size, void* d_ws, size_t ws_size,
                              hipStream_t stream) {
    const float* beta  = (const float*)d_in[0];
    const float* pose  = (const float*)d_in[1];
    const float* vtemp = (const float*)d_in[2];
    const float* sdirs = (const float*)d_in[3];
    const float* pdirs = (const float*)d_in[4];
    const float* jreg  = (const float*)d_in[5];
    const float* wts   = (const float*)d_in[6];
    char* ws = (char*)d_ws;
    float*    ws_part = (float*)(ws + O_PART);
    ushort_t* ws_G2   = (ushort_t*)(ws + O_G2);
    ushort_t* ws_A    = (ushort_t*)(ws + O_A);
    ushort_t* ws_W    = (ushort_t*)(ws + O_W);
    ushort_t* ws_B    = (ushort_t*)(ws + O_B);
    float* out = (float*)d_out;

    k_js<<<dim3(JS1_BLKS), dim3(256), 0, stream>>>(jreg, sdirs, vtemp, ws_part);
    k_prep<<<dim3(PREP_BLKS), dim3(256), 0, stream>>>(
        beta, pose, ws_part, pdirs, sdirs, wts, ws_G2, ws_A, ws_B, ws_W);
    k_fused<<<dim3(FUSE_BLKS), dim3(256), 0, stream>>>(ws_A, ws_B, ws_W, ws_G2, vtemp, out);
}